// Round 21
// baseline (60.934 us; speedup 1.0000x reference)
//
#include <hip/hip_runtime.h>
#include <math.h>

// Problem constants
#define BINS   256
#define NPAIR  24        // B*C = 8*3
#define NPIX   16384     // 128*128
#define SPLIT  16        // blocks per (tensor,channel)
#define NBLK   (48 * SPLIT)   // 768 blocks

#define DELTA    0.003921568859f           // 1/255 (bin pitch)
// exp2-folded constants
#define NK2      -7213.475204f             // -5000 * log2(e)
#define A2K2     56.57627611f              // (10000/255) * log2(e)
#define B2K2     0.11093398f               // 5000*DELTA^2 * log2(e)
#define RHO1     0.85745468f               // rho   = exp(-2*5000*DELTA^2)
#define RHO3     0.63042510f               // rho^3
#define RHO4     0.54056079f               // rho^4
#define INV_NORM 39.894228040143274f       // 1/(sigma*sqrt(2*pi))

typedef float v2f __attribute__((ext_vector_type(2)));

// ---------------------------------------------------------------------------
// MEASUREMENT ROUND (R21): exact R16 kernels (21.89 us champion), but hist is
// launched 4x back-to-back. Repeat launches write byte-identical data (pure
// function of inputs) — correctness and replay determinism unchanged.
// hist_dur ≈ (total − 21.89)/3 − 1.6us(node gap). Settles whether hist
// (five consecutive nulls) or klfused+overhead is the true remaining wall.
// ---------------------------------------------------------------------------
__global__ __launch_bounds__(256) void hist_kernel(
    const float* __restrict__ targ, const float* __restrict__ pred,
    float* __restrict__ g_part) {
  __shared__ float h[4][4][BINS];   // [wave][subgroup][bin] = 16 KiB
  __shared__ float pxs[1024];       // block's pixel slab

  const int t = threadIdx.x, lane = t & 63, wv = t >> 6;
  const int g = lane >> 4, lsub = lane & 15;
  const int pg = blockIdx.x >> 4;            // 0..47
  const int split = blockIdx.x & (SPLIT - 1);
  const int chan = (pg < NPAIR) ? pg : pg - NPAIR;
  const float* __restrict__ src = (pg < NPAIR) ? targ : pred;

  // stage 1024 pixels: 256 threads x float4 (coalesced, ds_write_b128)
  reinterpret_cast<float4*>(pxs)[t] =
      reinterpret_cast<const float4*>(src + chan * NPIX + split * 1024)[t];
  __syncthreads();

  const float c0 = (float)(16 * lsub) * DELTA;  // lane's first bin center
  const v2f RHO13 = {RHO1, RHO3};
  const v2f RHO44 = {RHO4, RHO4};

  v2f acc[8];
  #pragma unroll
  for (int i = 0; i < 8; ++i) acc[i] = (v2f){0.f, 0.f};

  #pragma unroll 2
  for (int r = 0; r < 32; ++r) {
    // subgroup g's two pixels this round (uniform per 16-lane subgroup)
    const float xA = pxs[wv * 256 + 8 * r + g];
    const float xB = pxs[wv * 256 + 8 * r + 4 + g];

    const float dA = xA - c0;
    const float dB = xB - c0;
    const float w0A = __builtin_amdgcn_exp2f(NK2 * dA * dA);
    const float w0B = __builtin_amdgcn_exp2f(NK2 * dB * dB);
    const float q0A = __builtin_amdgcn_exp2f(A2K2 * dA - B2K2);
    const float q0B = __builtin_amdgcn_exp2f(A2K2 * dB - B2K2);

    v2f wA; wA.x = w0A; wA.y = w0A * q0A;
    v2f wB; wB.x = w0B; wB.y = w0B * q0B;
    v2f mA = (q0A * q0A) * RHO13;
    v2f mB = (q0B * q0B) * RHO13;
    acc[0] += wA + wB;
    #pragma unroll
    for (int i = 1; i < 8; ++i) {
      wA *= mA; wB *= mB;      // two independent chains
      mA *= RHO44; mB *= RHO44;
      acc[i] += wA + wB;
    }
  }

  // block combine: 16 (wave,subgroup) partials -> one 256-bin block partial
  #pragma unroll
  for (int i = 0; i < 8; i += 2)
    reinterpret_cast<float4*>(&h[wv][g][16 * lsub + 2 * i])[0] =
        make_float4(acc[i].x, acc[i].y, acc[i + 1].x, acc[i + 1].y);
  __syncthreads();

  float s = 0.f;
  #pragma unroll
  for (int w2 = 0; w2 < 4; ++w2)
    #pragma unroll
    for (int g2 = 0; g2 < 4; ++g2) s += h[w2][g2][t];
  g_part[blockIdx.x * BINS + t] = s;          // blockIdx = pg*SPLIT+split
}

// ---------------------------------------------------------------------------
// Reductions
// ---------------------------------------------------------------------------
__device__ __forceinline__ float wave_allsum(float v) {
  #pragma unroll
  for (int off = 32; off > 0; off >>= 1) v += __shfl_xor(v, off, 64);
  return v;
}
__device__ __forceinline__ float block_sum(float v, float* red, int lane, int wv) {
  v = wave_allsum(v);
  __syncthreads();
  if (lane == 0) red[wv] = v;
  __syncthreads();
  return red[0] + red[1] + red[2] + red[3];
}

// ---------------------------------------------------------------------------
// Kernel 2: per-pair KL + fused final mean (R13/R16 pattern, proven).
// ---------------------------------------------------------------------------
__global__ __launch_bounds__(256) void klfused_kernel(
    const float* __restrict__ g_part, unsigned int* __restrict__ fl1,
    unsigned int* __restrict__ fl2, float* __restrict__ out) {
  const int t = threadIdx.x, lane = t & 63, wv = t >> 6;
  const int p = blockIdx.x;

  if (p < NPAIR) {
    __shared__ float red[4];
    float ht = 0.f, hq = 0.f;
    #pragma unroll
    for (int s = 0; s < SPLIT; ++s) {
      ht += g_part[(p * SPLIT + s) * BINS + t];
      hq += g_part[((NPAIR + p) * SPLIT + s) * BINS + t];
    }
    ht *= INV_NORM;
    hq *= INV_NORM;

    const float st = block_sum(ht, red, lane, wv);
    const float sq = block_sum(hq, red, lane, wv);
    const float P = ht / (st + 1e-10f) + 1e-10f;
    const float Q = hq / (sq + 1e-10f) + 1e-10f;
    const float kl = block_sum(P * __logf(P / Q), red, lane, wv);
    if (t == 0) {
      const unsigned int b = __float_as_uint(kl);
      __hip_atomic_store(&fl1[p], b, __ATOMIC_RELEASE, __HIP_MEMORY_SCOPE_AGENT);
      __hip_atomic_store(&fl2[p], ~b, __ATOMIC_RELEASE, __HIP_MEMORY_SCOPE_AGENT);
    }
  } else {
    // finisher block: wave 0 only
    if (t >= 64) return;
    float v = 0.f;
    if (lane < NPAIR) {
      unsigned int a, b;
      do {
        a = __hip_atomic_load(&fl1[lane], __ATOMIC_ACQUIRE, __HIP_MEMORY_SCOPE_AGENT);
        b = __hip_atomic_load(&fl2[lane], __ATOMIC_ACQUIRE, __HIP_MEMORY_SCOPE_AGENT);
      } while (b != ~a);
      v = __uint_as_float(a);
    }
    v = wave_allsum(v);
    if (lane == 0) out[0] = v * (1.0f / NPAIR);
  }
}

// ---------------------------------------------------------------------------
extern "C" void kernel_launch(void* const* d_in, const int* in_sizes, int n_in,
                              void* d_out, int out_size, void* d_ws, size_t ws_size,
                              hipStream_t stream) {
  const float* targ = (const float*)d_in[0];
  const float* pred = (const float*)d_in[1];
  float* g_part = (float*)d_ws;                       // 768*256 f32 = 768 KiB
  unsigned int* fl1 = (unsigned int*)(g_part + NBLK * BINS);  // 24 words
  unsigned int* fl2 = fl1 + NPAIR;                            // 24 words
  float* out = (float*)d_out;

  // 4x hist: repeats write identical bytes; Δtotal/3 isolates hist duration.
  hist_kernel<<<dim3(NBLK), dim3(256), 0, stream>>>(targ, pred, g_part);
  hist_kernel<<<dim3(NBLK), dim3(256), 0, stream>>>(targ, pred, g_part);
  hist_kernel<<<dim3(NBLK), dim3(256), 0, stream>>>(targ, pred, g_part);
  hist_kernel<<<dim3(NBLK), dim3(256), 0, stream>>>(targ, pred, g_part);
  klfused_kernel<<<dim3(NPAIR + 1), dim3(256), 0, stream>>>(g_part, fl1, fl2, out);
}

// Round 22
// 21.826 us; speedup vs baseline: 2.7918x; 2.7918x over previous
//
#include <hip/hip_runtime.h>
#include <math.h>

// Problem constants
#define BINS   256
#define NPAIR  24        // B*C = 8*3
#define NPIX   16384     // 128*128
#define SPLIT  16        // blocks per (tensor,channel)
#define NBLK   (48 * SPLIT)   // 768 blocks

#define DELTA    0.003921568859f           // 1/255 (bin pitch)
// exp2-folded constants
#define NK2      -7213.475204f             // -5000 * log2(e)
#define A2K2     56.57627611f              // (10000/255) * log2(e)
#define B2K2     0.11093398f               // 5000*DELTA^2 * log2(e)
#define RHO1     0.85745468f               // rho   = exp(-2*5000*DELTA^2)
#define RHO3     0.63042510f               // rho^3
#define RHO4     0.54056079f               // rho^4
#define INV_NORM 39.894228040143274f       // 1/(sigma*sqrt(2*pi))

typedef float v2f __attribute__((ext_vector_type(2)));

// ---------------------------------------------------------------------------
// Kernel 1: soft histogram (R16 math). R22 delta: 1-round-ahead software
// pipeline. R21 measured hist ≈ 12.5us vs ~6.7us ideal issue (~55% eff);
// the stall is the dependent round-head (ds_read ~120cyc -> 4 v_exp -> chain).
// Prefetch r+1's pixels AND compute r+1's exps before r's 42-instr pk-chain,
// so the chain covers the head latency explicitly.
// ---------------------------------------------------------------------------
__global__ __launch_bounds__(256) void hist_kernel(
    const float* __restrict__ targ, const float* __restrict__ pred,
    float* __restrict__ g_part) {
  __shared__ float h[4][4][BINS];   // [wave][subgroup][bin] = 16 KiB
  __shared__ float pxs[1024 + 8];   // +8 pad: last-round prefetch stays in-bounds

  const int t = threadIdx.x, lane = t & 63, wv = t >> 6;
  const int g = lane >> 4, lsub = lane & 15;
  const int pg = blockIdx.x >> 4;            // 0..47
  const int split = blockIdx.x & (SPLIT - 1);
  const int chan = (pg < NPAIR) ? pg : pg - NPAIR;
  const float* __restrict__ src = (pg < NPAIR) ? targ : pred;

  // stage 1024 pixels: 256 threads x float4 (coalesced)
  reinterpret_cast<float4*>(pxs)[t] =
      reinterpret_cast<const float4*>(src + chan * NPIX + split * 1024)[t];
  if (t < 2) pxs[1024 + t * 4 + g] = 0.f;    // init pad (any value; results dead)
  __syncthreads();

  const float c0 = (float)(16 * lsub) * DELTA;  // lane's first bin center
  const v2f RHO13 = {RHO1, RHO3};
  const v2f RHO44 = {RHO4, RHO4};

  v2f acc[8];
  #pragma unroll
  for (int i = 0; i < 8; ++i) acc[i] = (v2f){0.f, 0.f};

  const int base = wv * 256 + g;

  // round-0 head
  float xA = pxs[base], xB = pxs[base + 4];
  float dA = xA - c0, dB = xB - c0;
  float w0A = __builtin_amdgcn_exp2f(NK2 * dA * dA);
  float q0A = __builtin_amdgcn_exp2f(A2K2 * dA - B2K2);
  float w0B = __builtin_amdgcn_exp2f(NK2 * dB * dB);
  float q0B = __builtin_amdgcn_exp2f(A2K2 * dB - B2K2);

  #pragma unroll 2
  for (int r = 0; r < 32; ++r) {
    // ---- head of round r+1, issued BEFORE round r's chain ----
    const float xA2 = pxs[base + 8 * (r + 1)];
    const float xB2 = pxs[base + 8 * (r + 1) + 4];
    const float dA2 = xA2 - c0, dB2 = xB2 - c0;
    const float w0A2 = __builtin_amdgcn_exp2f(NK2 * dA2 * dA2);
    const float q0A2 = __builtin_amdgcn_exp2f(A2K2 * dA2 - B2K2);
    const float w0B2 = __builtin_amdgcn_exp2f(NK2 * dB2 * dB2);
    const float q0B2 = __builtin_amdgcn_exp2f(A2K2 * dB2 - B2K2);

    // ---- chain of round r (hides the latency above) ----
    v2f wA; wA.x = w0A; wA.y = w0A * q0A;
    v2f wB; wB.x = w0B; wB.y = w0B * q0B;
    v2f mA = (q0A * q0A) * RHO13;
    v2f mB = (q0B * q0B) * RHO13;
    acc[0] += wA + wB;
    #pragma unroll
    for (int i = 1; i < 8; ++i) {
      wA *= mA; wB *= mB;
      mA *= RHO44; mB *= RHO44;
      acc[i] += wA + wB;
    }

    // rotate
    w0A = w0A2; q0A = q0A2; w0B = w0B2; q0B = q0B2;
  }

  // block combine: 16 (wave,subgroup) partials -> one 256-bin block partial
  #pragma unroll
  for (int i = 0; i < 8; i += 2)
    reinterpret_cast<float4*>(&h[wv][g][16 * lsub + 2 * i])[0] =
        make_float4(acc[i].x, acc[i].y, acc[i + 1].x, acc[i + 1].y);
  __syncthreads();

  float s = 0.f;
  #pragma unroll
  for (int w2 = 0; w2 < 4; ++w2)
    #pragma unroll
    for (int g2 = 0; g2 < 4; ++g2) s += h[w2][g2][t];
  g_part[blockIdx.x * BINS + t] = s;          // blockIdx = pg*SPLIT+split
}

// ---------------------------------------------------------------------------
// Reductions
// ---------------------------------------------------------------------------
__device__ __forceinline__ float wave_allsum(float v) {
  #pragma unroll
  for (int off = 32; off > 0; off >>= 1) v += __shfl_xor(v, off, 64);
  return v;
}
__device__ __forceinline__ float block_sum(float v, float* red, int lane, int wv) {
  v = wave_allsum(v);
  __syncthreads();
  if (lane == 0) red[wv] = v;
  __syncthreads();
  return red[0] + red[1] + red[2] + red[3];
}

// ---------------------------------------------------------------------------
// Kernel 2: per-pair KL + fused final mean (R13/R16 pattern, proven).
// ---------------------------------------------------------------------------
__global__ __launch_bounds__(256) void klfused_kernel(
    const float* __restrict__ g_part, unsigned int* __restrict__ fl1,
    unsigned int* __restrict__ fl2, float* __restrict__ out) {
  const int t = threadIdx.x, lane = t & 63, wv = t >> 6;
  const int p = blockIdx.x;

  if (p < NPAIR) {
    __shared__ float red[4];
    float ht = 0.f, hq = 0.f;
    #pragma unroll
    for (int s = 0; s < SPLIT; ++s) {
      ht += g_part[(p * SPLIT + s) * BINS + t];
      hq += g_part[((NPAIR + p) * SPLIT + s) * BINS + t];
    }
    ht *= INV_NORM;
    hq *= INV_NORM;

    const float st = block_sum(ht, red, lane, wv);
    const float sq = block_sum(hq, red, lane, wv);
    const float P = ht / (st + 1e-10f) + 1e-10f;
    const float Q = hq / (sq + 1e-10f) + 1e-10f;
    const float kl = block_sum(P * __logf(P / Q), red, lane, wv);
    if (t == 0) {
      const unsigned int b = __float_as_uint(kl);
      __hip_atomic_store(&fl1[p], b, __ATOMIC_RELEASE, __HIP_MEMORY_SCOPE_AGENT);
      __hip_atomic_store(&fl2[p], ~b, __ATOMIC_RELEASE, __HIP_MEMORY_SCOPE_AGENT);
    }
  } else {
    // finisher block: wave 0 only
    if (t >= 64) return;
    float v = 0.f;
    if (lane < NPAIR) {
      unsigned int a, b;
      do {
        a = __hip_atomic_load(&fl1[lane], __ATOMIC_ACQUIRE, __HIP_MEMORY_SCOPE_AGENT);
        b = __hip_atomic_load(&fl2[lane], __ATOMIC_ACQUIRE, __HIP_MEMORY_SCOPE_AGENT);
      } while (b != ~a);
      v = __uint_as_float(a);
    }
    v = wave_allsum(v);
    if (lane == 0) out[0] = v * (1.0f / NPAIR);
  }
}

// ---------------------------------------------------------------------------
extern "C" void kernel_launch(void* const* d_in, const int* in_sizes, int n_in,
                              void* d_out, int out_size, void* d_ws, size_t ws_size,
                              hipStream_t stream) {
  const float* targ = (const float*)d_in[0];
  const float* pred = (const float*)d_in[1];
  float* g_part = (float*)d_ws;                       // 768*256 f32 = 768 KiB
  unsigned int* fl1 = (unsigned int*)(g_part + NBLK * BINS);  // 24 words
  unsigned int* fl2 = fl1 + NPAIR;                            // 24 words
  float* out = (float*)d_out;

  hist_kernel<<<dim3(NBLK), dim3(256), 0, stream>>>(targ, pred, g_part);
  klfused_kernel<<<dim3(NPAIR + 1), dim3(256), 0, stream>>>(g_part, fl1, fl2, out);
}